// Round 2
// baseline (3735.799 us; speedup 1.0000x reference)
//
#include <hip/hip_runtime.h>
#include <hip/hip_bf16.h>

#define N_USERS 6144
#define N_ITEMS 12288
#define N_NODES 18432
#define D 64
#define NNZ 589824
#define K_TOP 31   // K+1
#define NCAND 40   // fp32 pre-selection width (margin over 31)

// ---------------------------------------------------------------------------
// concat user_emb + item_emb -> e0 (fp64)
__global__ void concat64_kernel(const float* __restrict__ u,
                                const float* __restrict__ it,
                                double* __restrict__ e0) {
    int i = blockIdx.x * 256 + threadIdx.x;          // 0 .. N_NODES*D-1 exact
    const int NU = N_USERS * D;
    e0[i] = (i < NU) ? (double)u[i] : (double)it[i - NU];
}

// ---------------------------------------------------------------------------
// COO SpMM via fp64 atomics: y[row] += val * x[col], one wave per edge
__global__ void spmm64_kernel(const int* __restrict__ er, const int* __restrict__ ec,
                              const float* __restrict__ ev,
                              const double* __restrict__ x, double* __restrict__ y) {
    int gid = blockIdx.x * 256 + threadIdx.x;        // NNZ*64 = 37.7M < 2^31
    int e = gid >> 6;
    int d = gid & 63;
    int r = er[e];
    int c = ec[e];
    double v = (double)ev[e];
    atomicAdd(&y[(size_t)r * D + d], v * x[(size_t)c * D + d]);
}

// ---------------------------------------------------------------------------
// mean of (e0,e1,e2) for item rows + L2 normalize (fp64). One wave per row.
// Emits fp64 (for exact candidate recompute) and fp32 (for preselection GEMM).
__global__ void mean_norm64_kernel(const double* __restrict__ e0,
                                   const double* __restrict__ e1,
                                   const double* __restrict__ e2,
                                   double* __restrict__ xn64,
                                   float* __restrict__ xn32) {
    int t = threadIdx.x;
    int wave = t >> 6, lane = t & 63;
    int r = blockIdx.x * 4 + wave;                   // item row
    size_t g = (size_t)(r + N_USERS) * D + lane;
    double s = (e0[g] + e1[g] + e2[g]) / 3.0;
    double ss = s * s;
    #pragma unroll
    for (int off = 32; off; off >>= 1) ss += __shfl_xor(ss, off);
    double norm = sqrt(ss);
    double denom = fmax(norm, 1e-12);
    double v = s / denom;
    xn64[(size_t)r * D + lane] = v;
    xn32[(size_t)r * D + lane] = (float)v;
}

// ---------------------------------------------------------------------------
// C = X * X^T  (X: 12288x64 fp32 row-major) -> full sim matrix into d_out.
// Pre-selection only: values need ~1e-7 accuracy, not bit-exactness.
__global__ __launch_bounds__(256) void simgemm_kernel(const float* __restrict__ X,
                                                      float* __restrict__ C) {
    __shared__ __align__(16) float As[64][68];   // [k][m]
    __shared__ __align__(16) float Bs[64][68];   // [k][n]
    int tid = threadIdx.x;
    int bi = blockIdx.y, bj = blockIdx.x;
    const float* Abase = X + (size_t)bi * 64 * D;
    const float* Bbase = X + (size_t)bj * 64 * D;
    #pragma unroll
    for (int l = 0; l < 4; ++l) {
        int f4 = l * 256 + tid;
        int m  = f4 >> 4;
        int kk = (f4 & 15) << 2;
        float4 a = *(const float4*)(Abase + m * D + kk);
        As[kk + 0][m] = a.x; As[kk + 1][m] = a.y;
        As[kk + 2][m] = a.z; As[kk + 3][m] = a.w;
        float4 b = *(const float4*)(Bbase + m * D + kk);
        Bs[kk + 0][m] = b.x; Bs[kk + 1][m] = b.y;
        Bs[kk + 2][m] = b.z; Bs[kk + 3][m] = b.w;
    }
    __syncthreads();
    int tx = tid & 15, ty = tid >> 4;
    float acc[4][4] = {};
    #pragma unroll
    for (int k = 0; k < 64; ++k) {
        float4 a = *(const float4*)&As[k][ty << 2];
        float4 b = *(const float4*)&Bs[k][tx << 2];
        float av[4] = {a.x, a.y, a.z, a.w};
        float bv[4] = {b.x, b.y, b.z, b.w};
        #pragma unroll
        for (int i = 0; i < 4; ++i)
            #pragma unroll
            for (int j = 0; j < 4; ++j)
                acc[i][j] += av[i] * bv[j];
    }
    #pragma unroll
    for (int i = 0; i < 4; ++i) {
        size_t off = (size_t)(bi * 64 + (ty << 2) + i) * N_ITEMS + bj * 64 + (tx << 2);
        *(float4*)(C + off) = make_float4(acc[i][0], acc[i][1], acc[i][2], acc[i][3]);
    }
}

// ---------------------------------------------------------------------------
// Per-row: fp32 top-NCAND preselect -> fp64 recompute -> fp64 top-31 -> rewrite.
__global__ __launch_bounds__(256) void topk_kernel(float* __restrict__ C,
                                                   const double* __restrict__ xn64) {
    __shared__ __align__(16) float row[N_ITEMS];     // 48 KB
    __shared__ float rv[4];
    __shared__ int   ri[4];
    __shared__ int    candi[NCAND];
    __shared__ double candv[NCAND];
    __shared__ double selv[K_TOP];
    __shared__ int    seli[K_TOP];
    __shared__ int bcast_idx;
    int t = threadIdx.x;
    int r = blockIdx.x;
    float* Crow = C + (size_t)r * N_ITEMS;

    for (int i = t; i < N_ITEMS / 4; i += 256)
        ((float4*)row)[i] = ((const float4*)Crow)[i];
    __syncthreads();

    // per-thread cached max over strided slice {t, t+256, ...}
    float lv = -INFINITY; int li = 0x7fffffff;
    for (int i = t; i < N_ITEMS; i += 256) {
        float v = row[i];
        if (v > lv) { lv = v; li = i; }
    }

    for (int sel = 0; sel < NCAND; ++sel) {
        float v = lv; int idx = li;
        #pragma unroll
        for (int off = 32; off; off >>= 1) {
            float ov = __shfl_down(v, off);
            int   oi = __shfl_down(idx, off);
            if (ov > v || (ov == v && oi < idx)) { v = ov; idx = oi; }
        }
        if ((t & 63) == 0) { rv[t >> 6] = v; ri[t >> 6] = idx; }
        __syncthreads();
        if (t == 0) {
            float bv = rv[0]; int bi_ = ri[0];
            #pragma unroll
            for (int w = 1; w < 4; ++w)
                if (rv[w] > bv || (rv[w] == bv && ri[w] < bi_)) { bv = rv[w]; bi_ = ri[w]; }
            candi[sel] = bi_;
            bcast_idx = bi_;
            row[bi_] = -INFINITY;
        }
        __syncthreads();
        int bi_ = bcast_idx;
        if ((bi_ & 255) == t) {                      // owner re-scans its slice
            lv = -INFINITY; li = 0x7fffffff;
            for (int i = t; i < N_ITEMS; i += 256) {
                float v2 = row[i];
                if (v2 > lv) { lv = v2; li = i; }
            }
        }
    }
    __syncthreads();

    // exact fp64 recompute of the NCAND candidate dots
    if (t < NCAND) {
        int c = candi[t];
        const double* xr = xn64 + (size_t)r * D;
        const double* xc = xn64 + (size_t)c * D;
        double acc = 0.0;
        #pragma unroll 8
        for (int k = 0; k < D; ++k) acc += xr[k] * xc[k];
        candv[t] = acc;
    }
    __syncthreads();

    // wave 0: fp64 top-31 of the NCAND candidates (lower index wins ties)
    if (t < 64) {
        double v = (t < NCAND) ? candv[t] : -INFINITY;
        int idx = (t < NCAND) ? candi[t] : 0x7fffffff;
        for (int sel = 0; sel < K_TOP; ++sel) {
            double bv = v; int bi_ = idx;
            #pragma unroll
            for (int off = 32; off; off >>= 1) {
                double ov = __shfl_down(bv, off);
                int    oi = __shfl_down(bi_, off);
                if (ov > bv || (ov == bv && oi < bi_)) { bv = ov; bi_ = oi; }
            }
            bv = __shfl(bv, 0); bi_ = __shfl(bi_, 0);
            if (t == 0) { selv[sel] = bv; seli[sel] = bi_; }
            if (idx == bi_) v = -INFINITY;           // remove winner
        }
    }
    __syncthreads();

    for (int i = t; i < N_ITEMS / 4; i += 256)
        ((float4*)row)[i] = make_float4(0.f, 0.f, 0.f, 0.f);
    __syncthreads();
    if (t < K_TOP) {
        double v = selv[t];
        row[seli[t]] = (v > 0.0) ? (float)v : 0.f;
    }
    __syncthreads();
    for (int i = t; i < N_ITEMS / 4; i += 256)
        ((float4*)Crow)[i] = ((float4*)row)[i];
}

// ---------------------------------------------------------------------------
extern "C" void kernel_launch(void* const* d_in, const int* in_sizes, int n_in,
                              void* d_out, int out_size, void* d_ws, size_t ws_size,
                              hipStream_t stream) {
    const float* user_emb = (const float*)d_in[0];
    const float* item_emb = (const float*)d_in[1];
    const int*   edge_row = (const int*)d_in[2];
    const int*   edge_col = (const int*)d_in[3];
    const float* edge_val = (const float*)d_in[4];
    float* C = (float*)d_out;

    double* e0d  = (double*)d_ws;                    // 18432*64 doubles
    double* e1d  = e0d + (size_t)N_NODES * D;
    double* e2d  = e1d + (size_t)N_NODES * D;
    double* xn64 = e2d + (size_t)N_NODES * D;        // 12288*64 doubles
    float*  xn32 = (float*)(xn64 + (size_t)N_ITEMS * D);

    hipMemsetAsync(e1d, 0, (size_t)N_NODES * D * sizeof(double), stream);
    hipMemsetAsync(e2d, 0, (size_t)N_NODES * D * sizeof(double), stream);

    concat64_kernel<<<N_NODES * D / 256, 256, 0, stream>>>(user_emb, item_emb, e0d);

    spmm64_kernel<<<NNZ * 64 / 256, 256, 0, stream>>>(edge_row, edge_col, edge_val, e0d, e1d);
    spmm64_kernel<<<NNZ * 64 / 256, 256, 0, stream>>>(edge_row, edge_col, edge_val, e1d, e2d);

    mean_norm64_kernel<<<N_ITEMS / 4, 256, 0, stream>>>(e0d, e1d, e2d, xn64, xn32);

    dim3 ggrid(N_ITEMS / 64, N_ITEMS / 64);
    simgemm_kernel<<<ggrid, 256, 0, stream>>>(xn32, C);

    topk_kernel<<<N_ITEMS, 256, 0, stream>>>(C, xn64);
}

// Round 3
// 1321.581 us; speedup vs baseline: 2.8268x; 2.8268x over previous
//
#include <hip/hip_runtime.h>
#include <hip/hip_bf16.h>

#define N_USERS 6144
#define N_ITEMS 12288
#define N_NODES 18432
#define D 64
#define NNZ 589824
#define K_TOP 31     // K+1
#define NCAND_MIN 40 // fp32 preselect margin over 31
#define NCAND_MAX 224
#define CMAX 256

// ---------------------------------------------------------------------------
// concat user_emb + item_emb -> e0 (fp64)
__global__ void concat64_kernel(const float* __restrict__ u,
                                const float* __restrict__ it,
                                double* __restrict__ e0) {
    int i = blockIdx.x * 256 + threadIdx.x;
    const int NU = N_USERS * D;
    e0[i] = (i < NU) ? (double)u[i] : (double)it[i - NU];
}

// ---------------------------------------------------------------------------
// CSR build: count, scan, scatter
__global__ void count_kernel(const int* __restrict__ er, int* __restrict__ cnt) {
    int e = blockIdx.x * 256 + threadIdx.x;
    atomicAdd(&cnt[er[e]], 1);
}

__global__ __launch_bounds__(256) void scan_kernel(const int* __restrict__ cnt,
                                                   int* __restrict__ row_start,
                                                   int* __restrict__ cursor) {
    __shared__ int part[256];
    int t = threadIdx.x;
    const int PER = N_NODES / 256;                   // 72
    int s = 0;
    for (int i = 0; i < PER; ++i) s += cnt[t * PER + i];
    part[t] = s;
    __syncthreads();
    // Hillis-Steele inclusive scan
    for (int off = 1; off < 256; off <<= 1) {
        int v = part[t];
        int w = (t >= off) ? part[t - off] : 0;
        __syncthreads();
        part[t] = v + w;
        __syncthreads();
    }
    int run = (t == 0) ? 0 : part[t - 1];
    for (int i = 0; i < PER; ++i) {
        int idx = t * PER + i;
        row_start[idx] = run;
        cursor[idx] = run;
        run += cnt[idx];
    }
    if (t == 255) row_start[N_NODES] = run;          // == NNZ
}

__global__ void scatter_kernel(const int* __restrict__ er, const int* __restrict__ ec,
                               const float* __restrict__ ev,
                               int* __restrict__ cursor,
                               int* __restrict__ ecol_s, float* __restrict__ eval_s) {
    int e = blockIdx.x * 256 + threadIdx.x;
    int r = er[e];
    int pos = atomicAdd(&cursor[r], 1);
    ecol_s[pos] = ec[e];
    eval_s[pos] = ev[e];
}

// ---------------------------------------------------------------------------
// CSR SpMM, fp64, no atomics: one wave per row, lane = dim
__global__ __launch_bounds__(256) void spmm_csr_kernel(const int* __restrict__ row_start,
                                                       const int* __restrict__ ecol_s,
                                                       const float* __restrict__ eval_s,
                                                       const double* __restrict__ x,
                                                       double* __restrict__ y) {
    int t = threadIdx.x;
    int lane = t & 63, wave = t >> 6;
    int row = blockIdx.x * 4 + wave;
    if (row >= N_NODES) return;
    int beg = row_start[row], end = row_start[row + 1];
    double acc = 0.0;
    for (int j = beg; j < end; ++j) {
        int c = ecol_s[j];
        double v = (double)eval_s[j];
        acc += v * x[(size_t)c * D + lane];
    }
    y[(size_t)row * D + lane] = acc;
}

// ---------------------------------------------------------------------------
// mean of (e0,e1,e2) for item rows + L2 normalize (fp64). One wave per row.
__global__ void mean_norm64_kernel(const double* __restrict__ e0,
                                   const double* __restrict__ e1,
                                   const double* __restrict__ e2,
                                   double* __restrict__ xn64,
                                   float* __restrict__ xn32) {
    int t = threadIdx.x;
    int wave = t >> 6, lane = t & 63;
    int r = blockIdx.x * 4 + wave;
    size_t g = (size_t)(r + N_USERS) * D + lane;
    double s = (e0[g] + e1[g] + e2[g]) / 3.0;
    double ss = s * s;
    #pragma unroll
    for (int off = 32; off; off >>= 1) ss += __shfl_xor(ss, off);
    double norm = sqrt(ss);
    double denom = fmax(norm, 1e-12);
    double v = s / denom;
    xn64[(size_t)r * D + lane] = v;
    xn32[(size_t)r * D + lane] = (float)v;
}

// ---------------------------------------------------------------------------
// C = X * X^T  (fp32 preselection values; ~1e-7 accuracy is enough)
__global__ __launch_bounds__(256) void simgemm_kernel(const float* __restrict__ X,
                                                      float* __restrict__ C) {
    __shared__ __align__(16) float As[64][68];
    __shared__ __align__(16) float Bs[64][68];
    int tid = threadIdx.x;
    int bi = blockIdx.y, bj = blockIdx.x;
    const float* Abase = X + (size_t)bi * 64 * D;
    const float* Bbase = X + (size_t)bj * 64 * D;
    #pragma unroll
    for (int l = 0; l < 4; ++l) {
        int f4 = l * 256 + tid;
        int m  = f4 >> 4;
        int kk = (f4 & 15) << 2;
        float4 a = *(const float4*)(Abase + m * D + kk);
        As[kk + 0][m] = a.x; As[kk + 1][m] = a.y;
        As[kk + 2][m] = a.z; As[kk + 3][m] = a.w;
        float4 b = *(const float4*)(Bbase + m * D + kk);
        Bs[kk + 0][m] = b.x; Bs[kk + 1][m] = b.y;
        Bs[kk + 2][m] = b.z; Bs[kk + 3][m] = b.w;
    }
    __syncthreads();
    int tx = tid & 15, ty = tid >> 4;
    float acc[4][4] = {};
    #pragma unroll
    for (int k = 0; k < 64; ++k) {
        float4 a = *(const float4*)&As[k][ty << 2];
        float4 b = *(const float4*)&Bs[k][tx << 2];
        float av[4] = {a.x, a.y, a.z, a.w};
        float bv[4] = {b.x, b.y, b.z, b.w};
        #pragma unroll
        for (int i = 0; i < 4; ++i)
            #pragma unroll
            for (int j = 0; j < 4; ++j)
                acc[i][j] += av[i] * bv[j];
    }
    #pragma unroll
    for (int i = 0; i < 4; ++i) {
        size_t off = (size_t)(bi * 64 + (ty << 2) + i) * N_ITEMS + bj * 64 + (tx << 2);
        *(float4*)(C + off) = make_float4(acc[i][0], acc[i][1], acc[i][2], acc[i][3]);
    }
}

// ---------------------------------------------------------------------------
// Per-row top-31: register-resident radix-bisection preselect (fp32 bits),
// fp64 recompute of <=CMAX candidates, parallel rank-by-count selection.
__global__ __launch_bounds__(256) void topk_kernel(float* __restrict__ C,
                                                   const double* __restrict__ xn64) {
    __shared__ int s_red[4];
    __shared__ unsigned s_cnt;
    __shared__ int    candi[CMAX];
    __shared__ double candv[CMAX];
    __shared__ double s_xr[D];
    int t = threadIdx.x;
    int r = blockIdx.x;
    float4* Crow4 = (float4*)(C + (size_t)r * N_ITEMS);

    // 48 elements per thread, coalesced float4 loads
    unsigned u[48];
    #pragma unroll
    for (int j = 0; j < 12; ++j) {
        float4 f = Crow4[t + 256 * j];
        const float* p = &f.x;
        #pragma unroll
        for (int q = 0; q < 4; ++q) {
            unsigned b = __float_as_uint(p[q]);
            u[j * 4 + q] = b ^ ((b & 0x80000000u) ? 0xFFFFFFFFu : 0x80000000u);
        }
    }
    if (t < D) s_xr[t] = xn64[(size_t)r * D + t];

    // bisection on bit-space for threshold T with count(u>=T) in [40,224]
    unsigned lo = 0u, hi = 0xFFFFFFFFu, T = 0u, bestT = 0u;
    int found = 0;
    for (int it = 0; it < 32; ++it) {
        if (found || lo > hi) { __syncthreads(); __syncthreads(); continue; }
        unsigned mid = lo + ((hi - lo) >> 1);
        int c = 0;
        #pragma unroll
        for (int k = 0; k < 48; ++k) c += (u[k] >= mid) ? 1 : 0;
        #pragma unroll
        for (int off = 32; off; off >>= 1) c += __shfl_down(c, off);
        if ((t & 63) == 0) s_red[t >> 6] = c;
        __syncthreads();
        int ctot = s_red[0] + s_red[1] + s_red[2] + s_red[3];
        __syncthreads();                              // s_red reuse next iter
        if (ctot >= NCAND_MIN) {
            bestT = mid;
            if (ctot <= NCAND_MAX) { T = mid; found = 1; }
            else lo = mid + 1;
        } else {
            if (mid == 0u) { lo = 1u; hi = 0u; }      // collapse
            else hi = mid - 1;
        }
    }
    if (!found) T = bestT;

    if (t == 0) s_cnt = 0;
    __syncthreads();
    #pragma unroll
    for (int k = 0; k < 48; ++k) {
        if (u[k] >= T) {
            unsigned pos = atomicAdd(&s_cnt, 1u);
            if (pos < CMAX) candi[pos] = (t + 256 * (k >> 2)) * 4 + (k & 3);
        }
    }
    __syncthreads();
    int c = (int)s_cnt; if (c > CMAX) c = CMAX;

    // fp64 recompute of candidate dots
    if (t < c) {
        const double* xc = xn64 + (size_t)candi[t] * D;
        double acc = 0.0;
        #pragma unroll 8
        for (int k = 0; k < D; ++k) acc += s_xr[k] * xc[k];
        candv[t] = acc;
    }
    __syncthreads();

    // rank-by-count: exact fp64 top-31, ties -> lower index (parallel, no barriers)
    int   sel_idx = -1;
    float sel_val = 0.f;
    if (t < c) {
        double v = candv[t];
        int    id = candi[t];
        int rank = 0;
        for (int j = 0; j < c; ++j) {
            double vj = candv[j];
            rank += (vj > v || (vj == v && candi[j] < id)) ? 1 : 0;
        }
        if (rank < K_TOP) {
            sel_idx = id;
            sel_val = (v > 0.0) ? (float)v : 0.f;
        }
    }

    // write zeros, then scatter the selected (barrier orders WAW on same cells)
    float4 z = make_float4(0.f, 0.f, 0.f, 0.f);
    #pragma unroll
    for (int j = 0; j < 12; ++j) Crow4[t + 256 * j] = z;
    __syncthreads();
    if (sel_idx >= 0) C[(size_t)r * N_ITEMS + sel_idx] = sel_val;
}

// ---------------------------------------------------------------------------
extern "C" void kernel_launch(void* const* d_in, const int* in_sizes, int n_in,
                              void* d_out, int out_size, void* d_ws, size_t ws_size,
                              hipStream_t stream) {
    const float* user_emb = (const float*)d_in[0];
    const float* item_emb = (const float*)d_in[1];
    const int*   edge_row = (const int*)d_in[2];
    const int*   edge_col = (const int*)d_in[3];
    const float* edge_val = (const float*)d_in[4];
    float* C = (float*)d_out;

    // fp64 arrays first (alignment)
    double* e0d  = (double*)d_ws;                        // 18432*64
    double* e1d  = e0d + (size_t)N_NODES * D;
    double* e2d  = e1d + (size_t)N_NODES * D;
    double* xn64 = e2d + (size_t)N_NODES * D;            // 12288*64
    float*  xn32 = (float*)(xn64 + (size_t)N_ITEMS * D); // 12288*64
    float*  eval_s = xn32 + (size_t)N_ITEMS * D;         // NNZ
    int*    ecol_s = (int*)(eval_s + NNZ);               // NNZ
    int*    cnt      = ecol_s + NNZ;                     // N_NODES
    int*    row_start = cnt + N_NODES;                   // N_NODES+1
    int*    cursor    = row_start + N_NODES + 1;         // N_NODES

    hipMemsetAsync(cnt, 0, N_NODES * sizeof(int), stream);

    concat64_kernel<<<N_NODES * D / 256, 256, 0, stream>>>(user_emb, item_emb, e0d);

    count_kernel<<<NNZ / 256, 256, 0, stream>>>(edge_row, cnt);
    scan_kernel<<<1, 256, 0, stream>>>(cnt, row_start, cursor);
    scatter_kernel<<<NNZ / 256, 256, 0, stream>>>(edge_row, edge_col, edge_val,
                                                  cursor, ecol_s, eval_s);

    spmm_csr_kernel<<<(N_NODES + 3) / 4, 256, 0, stream>>>(row_start, ecol_s, eval_s, e0d, e1d);
    spmm_csr_kernel<<<(N_NODES + 3) / 4, 256, 0, stream>>>(row_start, ecol_s, eval_s, e1d, e2d);

    mean_norm64_kernel<<<N_ITEMS / 4, 256, 0, stream>>>(e0d, e1d, e2d, xn64, xn32);

    dim3 ggrid(N_ITEMS / 64, N_ITEMS / 64);
    simgemm_kernel<<<ggrid, 256, 0, stream>>>(xn32, C);

    topk_kernel<<<N_ITEMS, 256, 0, stream>>>(C, xn64);
}

// Round 4
// 1003.938 us; speedup vs baseline: 3.7211x; 1.3164x over previous
//
#include <hip/hip_runtime.h>
#include <hip/hip_bf16.h>

#define N_USERS 6144
#define N_ITEMS 12288
#define N_NODES 18432
#define D 64
#define NNZ 589824
#define K_TOP 31     // K+1
#define NCAND_MIN 48 // bf16 preselect margin over 31
#define NCAND_MAX 240
#define CMAX 256

using frag_ab = __attribute__((ext_vector_type(8))) short;  // 8 bf16
using frag_cd = __attribute__((ext_vector_type(4))) float;  // 4 fp32

__device__ inline ushort f32_to_bf16_bits(float f) {
    unsigned b = __float_as_uint(f);
    unsigned r = (b + 0x7FFFu + ((b >> 16) & 1u)) >> 16;    // RNE
    return (ushort)r;
}

// ---------------------------------------------------------------------------
// concat user_emb + item_emb -> e0 (fp64)
__global__ void concat64_kernel(const float* __restrict__ u,
                                const float* __restrict__ it,
                                double* __restrict__ e0) {
    int i = blockIdx.x * 256 + threadIdx.x;
    const int NU = N_USERS * D;
    e0[i] = (i < NU) ? (double)u[i] : (double)it[i - NU];
}

// ---------------------------------------------------------------------------
// CSR build: count, scan, scatter
__global__ void count_kernel(const int* __restrict__ er, int* __restrict__ cnt) {
    int e = blockIdx.x * 256 + threadIdx.x;
    atomicAdd(&cnt[er[e]], 1);
}

__global__ __launch_bounds__(256) void scan_kernel(const int* __restrict__ cnt,
                                                   int* __restrict__ row_start,
                                                   int* __restrict__ cursor) {
    __shared__ int part[256];
    int t = threadIdx.x;
    const int PER = N_NODES / 256;                   // 72
    int s = 0;
    for (int i = 0; i < PER; ++i) s += cnt[t * PER + i];
    part[t] = s;
    __syncthreads();
    for (int off = 1; off < 256; off <<= 1) {
        int v = part[t];
        int w = (t >= off) ? part[t - off] : 0;
        __syncthreads();
        part[t] = v + w;
        __syncthreads();
    }
    int run = (t == 0) ? 0 : part[t - 1];
    for (int i = 0; i < PER; ++i) {
        int idx = t * PER + i;
        row_start[idx] = run;
        cursor[idx] = run;
        run += cnt[idx];
    }
    if (t == 255) row_start[N_NODES] = run;
}

__global__ void scatter_kernel(const int* __restrict__ er, const int* __restrict__ ec,
                               const float* __restrict__ ev,
                               int* __restrict__ cursor,
                               int* __restrict__ ecol_s, float* __restrict__ eval_s) {
    int e = blockIdx.x * 256 + threadIdx.x;
    int r = er[e];
    int pos = atomicAdd(&cursor[r], 1);
    ecol_s[pos] = ec[e];
    eval_s[pos] = ev[e];
}

// ---------------------------------------------------------------------------
// CSR SpMM, fp64, no atomics: one wave per row, lane = dim
__global__ __launch_bounds__(256) void spmm_csr_kernel(const int* __restrict__ row_start,
                                                       const int* __restrict__ ecol_s,
                                                       const float* __restrict__ eval_s,
                                                       const double* __restrict__ x,
                                                       double* __restrict__ y) {
    int t = threadIdx.x;
    int lane = t & 63, wave = t >> 6;
    int row = blockIdx.x * 4 + wave;
    if (row >= N_NODES) return;
    int beg = row_start[row], end = row_start[row + 1];
    double acc = 0.0;
    for (int j = beg; j < end; ++j) {
        int c = ecol_s[j];
        double v = (double)eval_s[j];
        acc += v * x[(size_t)c * D + lane];
    }
    y[(size_t)row * D + lane] = acc;
}

// ---------------------------------------------------------------------------
// mean + L2 normalize (fp64). Emits fp64 (exact recompute) and bf16 (MFMA).
__global__ void mean_norm64_kernel(const double* __restrict__ e0,
                                   const double* __restrict__ e1,
                                   const double* __restrict__ e2,
                                   double* __restrict__ xn64,
                                   ushort* __restrict__ xh) {
    int t = threadIdx.x;
    int wave = t >> 6, lane = t & 63;
    int r = blockIdx.x * 4 + wave;
    size_t g = (size_t)(r + N_USERS) * D + lane;
    double s = (e0[g] + e1[g] + e2[g]) / 3.0;
    double ss = s * s;
    #pragma unroll
    for (int off = 32; off; off >>= 1) ss += __shfl_xor(ss, off);
    double norm = sqrt(ss);
    double denom = fmax(norm, 1e-12);
    double v = s / denom;
    xn64[(size_t)r * D + lane] = v;
    xh[(size_t)r * D + lane] = f32_to_bf16_bits((float)v);
}

// ---------------------------------------------------------------------------
// Cb = bf16(Xh * Xh^T).  Xh: 12288x64 bf16 row-major.  128x128 tile / block,
// 4 waves, each wave 64x64 (4x4 tiles of 16x16x32 MFMA, K=64 -> 2 k-steps).
#define LDS_STRIDE 72   // shorts; 144 B rows -> 2-way bank conflict only (free)
__global__ __launch_bounds__(256) void simgemm_kernel(const ushort* __restrict__ Xh,
                                                      ushort* __restrict__ Cb) {
    __shared__ __align__(16) ushort Als[128 * LDS_STRIDE];
    __shared__ __align__(16) ushort Bls[128 * LDS_STRIDE];
    int t = threadIdx.x;
    int bi = blockIdx.y, bj = blockIdx.x;

    // stage A (rows bi*128..) and B (rows bj*128..): 8 uint4 per thread
    #pragma unroll
    for (int p = 0; p < 4; ++p) {
        int u4 = t + 256 * p;            // 0..1023
        int row = u4 >> 3;               // 8 uint4 per 64-short row
        int seg = u4 & 7;
        *(uint4*)&Als[row * LDS_STRIDE + seg * 8] =
            *(const uint4*)&Xh[(size_t)(bi * 128 + row) * D + seg * 8];
        *(uint4*)&Bls[row * LDS_STRIDE + seg * 8] =
            *(const uint4*)&Xh[(size_t)(bj * 128 + row) * D + seg * 8];
    }
    __syncthreads();

    int lane = t & 63, wave = t >> 6;
    int wrow = (wave >> 1) * 64, wcol = (wave & 1) * 64;
    int ml = lane & 15, quad = lane >> 4;

    frag_cd acc[4][4] = {};
    #pragma unroll
    for (int s = 0; s < 2; ++s) {
        frag_ab af[4], bf[4];
        int koff = s * 32 + quad * 8;
        #pragma unroll
        for (int rt = 0; rt < 4; ++rt)
            af[rt] = *(const frag_ab*)&Als[(wrow + rt * 16 + ml) * LDS_STRIDE + koff];
        #pragma unroll
        for (int ct = 0; ct < 4; ++ct)
            bf[ct] = *(const frag_ab*)&Bls[(wcol + ct * 16 + ml) * LDS_STRIDE + koff];
        #pragma unroll
        for (int rt = 0; rt < 4; ++rt)
            #pragma unroll
            for (int ct = 0; ct < 4; ++ct)
                acc[rt][ct] = __builtin_amdgcn_mfma_f32_16x16x32_bf16(
                    af[rt], bf[ct], acc[rt][ct], 0, 0, 0);
    }

    // epilogue: D row = quad*4+reg, col = ml (m89-verified)
    #pragma unroll
    for (int rt = 0; rt < 4; ++rt) {
        #pragma unroll
        for (int ct = 0; ct < 4; ++ct) {
            size_t gr = (size_t)(bi * 128 + wrow + rt * 16 + quad * 4);
            int    gc = bj * 128 + wcol + ct * 16 + ml;
            #pragma unroll
            for (int r = 0; r < 4; ++r)
                Cb[(gr + r) * N_ITEMS + gc] = f32_to_bf16_bits(acc[rt][ct][r]);
        }
    }
}

// ---------------------------------------------------------------------------
// Per-row top-31 from bf16 sim: 16-bit radix-bisection preselect (register-
// resident), fp64 recompute of <=CMAX candidates, rank-by-count selection.
__global__ __launch_bounds__(256) void topk_kernel(const ushort* __restrict__ Cb,
                                                   float* __restrict__ Cout,
                                                   const double* __restrict__ xn64) {
    __shared__ int s_red[4];
    __shared__ unsigned s_cnt;
    __shared__ int    candi[CMAX];
    __shared__ double candv[CMAX];
    __shared__ double s_xr[D];
    int t = threadIdx.x;
    int r = blockIdx.x;
    const uint4* Crow4 = (const uint4*)(Cb + (size_t)r * N_ITEMS);  // 1536 uint4

    // 48 bf16 per thread -> order-preserving u16 keys
    unsigned short u[48];
    #pragma unroll
    for (int j = 0; j < 6; ++j) {
        uint4 f = Crow4[t + 256 * j];
        const unsigned* w = &f.x;
        #pragma unroll
        for (int q = 0; q < 4; ++q) {
            unsigned lo = w[q] & 0xFFFFu, hi = w[q] >> 16;
            u[j * 8 + 2 * q]     = (unsigned short)(lo ^ ((lo & 0x8000u) ? 0xFFFFu : 0x8000u));
            u[j * 8 + 2 * q + 1] = (unsigned short)(hi ^ ((hi & 0x8000u) ? 0xFFFFu : 0x8000u));
        }
    }
    if (t < D) s_xr[t] = xn64[(size_t)r * D + t];

    // bisection on 16-bit key space for count(u>=T) in [NCAND_MIN, NCAND_MAX]
    unsigned lo = 0u, hi = 0xFFFFu, T = 0u, bestT = 0u;
    int found = 0;
    for (int it = 0; it < 16; ++it) {
        if (found || lo > hi) { __syncthreads(); __syncthreads(); continue; }
        unsigned mid = lo + ((hi - lo) >> 1);
        int c = 0;
        #pragma unroll
        for (int k = 0; k < 48; ++k) c += (u[k] >= mid) ? 1 : 0;
        #pragma unroll
        for (int off = 32; off; off >>= 1) c += __shfl_down(c, off);
        if ((t & 63) == 0) s_red[t >> 6] = c;
        __syncthreads();
        int ctot = s_red[0] + s_red[1] + s_red[2] + s_red[3];
        __syncthreads();
        if (ctot >= NCAND_MIN) {
            bestT = mid;
            if (ctot <= NCAND_MAX) { T = mid; found = 1; }
            else lo = mid + 1;
        } else {
            if (mid == 0u) { lo = 1u; hi = 0u; }
            else hi = mid - 1;
        }
    }
    if (!found) T = bestT;

    if (t == 0) s_cnt = 0;
    __syncthreads();
    #pragma unroll
    for (int k = 0; k < 48; ++k) {
        if (u[k] >= (unsigned short)T) {
            unsigned pos = atomicAdd(&s_cnt, 1u);
            if (pos < CMAX) candi[pos] = 8 * (t + 256 * (k >> 3)) + (k & 7);
        }
    }
    __syncthreads();
    int c = (int)s_cnt; if (c > CMAX) c = CMAX;

    // fp64 recompute of candidate dots
    if (t < c) {
        const double* xc = xn64 + (size_t)candi[t] * D;
        double acc = 0.0;
        #pragma unroll 8
        for (int k = 0; k < D; ++k) acc += s_xr[k] * xc[k];
        candv[t] = acc;
    }
    __syncthreads();

    // rank-by-count: exact fp64 top-31, ties -> lower index
    int   sel_idx = -1;
    float sel_val = 0.f;
    if (t < c) {
        double v = candv[t];
        int    id = candi[t];
        int rank = 0;
        for (int j = 0; j < c; ++j) {
            double vj = candv[j];
            rank += (vj > v || (vj == v && candi[j] < id)) ? 1 : 0;
        }
        if (rank < K_TOP) {
            sel_idx = id;
            sel_val = (v > 0.0) ? (float)v : 0.f;
        }
    }

    // write zeros, then scatter selected (barrier orders WAW)
    float4* Orow4 = (float4*)(Cout + (size_t)r * N_ITEMS);
    float4 z = make_float4(0.f, 0.f, 0.f, 0.f);
    #pragma unroll
    for (int j = 0; j < 12; ++j) Orow4[t + 256 * j] = z;
    __syncthreads();
    if (sel_idx >= 0) Cout[(size_t)r * N_ITEMS + sel_idx] = sel_val;
}

// ---------------------------------------------------------------------------
extern "C" void kernel_launch(void* const* d_in, const int* in_sizes, int n_in,
                              void* d_out, int out_size, void* d_ws, size_t ws_size,
                              hipStream_t stream) {
    const float* user_emb = (const float*)d_in[0];
    const float* item_emb = (const float*)d_in[1];
    const int*   edge_row = (const int*)d_in[2];
    const int*   edge_col = (const int*)d_in[3];
    const float* edge_val = (const float*)d_in[4];
    float* C = (float*)d_out;

    double* e0d  = (double*)d_ws;                        // N_NODES*D
    double* e1d  = e0d + (size_t)N_NODES * D;
    double* e2d  = e1d + (size_t)N_NODES * D;
    double* xn64 = e2d + (size_t)N_NODES * D;            // N_ITEMS*D
    ushort* xh   = (ushort*)(xn64 + (size_t)N_ITEMS * D);// N_ITEMS*D bf16
    ushort* Cb   = xh + (size_t)N_ITEMS * D;             // N_ITEMS^2 bf16 (302 MB)
    float*  eval_s = (float*)(Cb + (size_t)N_ITEMS * N_ITEMS);
    int*    ecol_s = (int*)(eval_s + NNZ);
    int*    cnt       = ecol_s + NNZ;
    int*    row_start = cnt + N_NODES;
    int*    cursor    = row_start + N_NODES + 1;

    hipMemsetAsync(cnt, 0, N_NODES * sizeof(int), stream);

    concat64_kernel<<<N_NODES * D / 256, 256, 0, stream>>>(user_emb, item_emb, e0d);

    count_kernel<<<NNZ / 256, 256, 0, stream>>>(edge_row, cnt);
    scan_kernel<<<1, 256, 0, stream>>>(cnt, row_start, cursor);
    scatter_kernel<<<NNZ / 256, 256, 0, stream>>>(edge_row, edge_col, edge_val,
                                                  cursor, ecol_s, eval_s);

    spmm_csr_kernel<<<(N_NODES + 3) / 4, 256, 0, stream>>>(row_start, ecol_s, eval_s, e0d, e1d);
    spmm_csr_kernel<<<(N_NODES + 3) / 4, 256, 0, stream>>>(row_start, ecol_s, eval_s, e1d, e2d);

    mean_norm64_kernel<<<N_ITEMS / 4, 256, 0, stream>>>(e0d, e1d, e2d, xn64, xh);

    dim3 ggrid(N_ITEMS / 128, N_ITEMS / 128);
    simgemm_kernel<<<ggrid, 256, 0, stream>>>(xh, Cb);

    topk_kernel<<<N_ITEMS, 256, 0, stream>>>(Cb, C, xn64);
}